// Round 8
// baseline (158.815 us; speedup 1.0000x reference)
//
#include <hip/hip_runtime.h>

#define BATCH 128
#define M 259
#define D 512
#define T 256
#define NM (BATCH * M)          // 33152
#define OUTHALF (BATCH * T * D)

typedef __bf16 bf16;
typedef __bf16 bf16x4 __attribute__((ext_vector_type(4)));
typedef __bf16 bf16x8 __attribute__((ext_vector_type(8)));
typedef float f32x4 __attribute__((ext_vector_type(4)));

// ws float layout: wcol[NM] | wrow[NM]

// Raw barriers: NO compiler vmcnt(0) drain (that drain is the 2-phase wall).
// BARRIER_FULL: ds_write visibility (lgkmcnt only). BARRIER_LIGHT: ordering only.
#define BARRIER_FULL()  do { asm volatile("s_waitcnt lgkmcnt(0)" ::: "memory"); \
    __builtin_amdgcn_s_barrier(); asm volatile("" ::: "memory"); } while (0)
#define BARRIER_LIGHT() do { asm volatile("" ::: "memory"); \
    __builtin_amdgcn_s_barrier(); asm volatile("" ::: "memory"); } while (0)

// ---------------- Kernel 0: zero the accumulators ----------------
__global__ void k_zero(float4* __restrict__ ws4) {
    int i = blockIdx.x * 256 + threadIdx.x;
    if (i < (2 * NM + 3) / 4) ws4[i] = make_float4(0.f, 0.f, 0.f, 0.f);
}

// ---------------- Kernel 1: fused norms + bf16 MFMA pairwise ---------------
// Async-staged: tile t+1's global loads are issued mid-iter and stay in
// flight across BOTH raw barriers + the MFMA phase (no vmcnt drain).
#define BT 96
#define BK 64
#define NTL 3   // 3*96 = 288 >= 259

__launch_bounds__(256)
__global__ void k_pairs(const float* __restrict__ x1, const float* __restrict__ x2,
                        float* __restrict__ ws) {
    __shared__ __align__(16) bf16 As[2][BT * BK];   // 24 KB
    __shared__ __align__(16) bf16 Bs[2][BT * BK];   // 24 KB
    __shared__ float na_s[BT];
    __shared__ float nb_s[BT];

    // XCD-aware bijective swizzle: 1152 blocks = 8 * 144
    int s   = blockIdx.x;
    int bid = (s & 7) * 144 + (s >> 3);
    int b   = bid / 9;
    int ti  = (bid % 9) / 3;
    int tj  = bid % 3;
    int i0  = ti * BT, j0 = tj * BT;

    int t    = threadIdx.x;
    int lane = t & 63;
    int w    = t >> 6;
    int wm   = w >> 1, wn = w & 1;
    int iw   = i0 + wm * 48;
    int jw   = j0 + wn * 48;

    const float* Ab = x1 + (size_t)b * M * D;
    const float* Bb = x2 + (size_t)b * M * D;

    // staging: 6 passes of 16 rows x 64 cols per matrix, 1 float4/thread/pass
    const float* pa[6];
    const float* pb[6];
    int c4 = (t & 15) * 4;
#pragma unroll
    for (int p = 0; p < 6; ++p) {
        int ra = min(i0 + p * 16 + (t >> 4), M - 1);
        int rb = min(j0 + p * 16 + (t >> 4), M - 1);
        pa[p] = Ab + (size_t)ra * D + c4;
        pb[p] = Bb + (size_t)rb * D + c4;
    }
    int wslot   = (t & 15) >> 1;
    int wwithin = (t & 1) * 4;
    int wr_off[6];
#pragma unroll
    for (int p = 0; p < 6; ++p) {
        int row = p * 16 + (t >> 4);
        wr_off[p] = row * BK + ((wslot ^ (row & 7)) << 3) + wwithin;
    }

    // fragment read offsets (element units), swizzle-matched (proven)
    int a_off[3][2], b_off[3][2];
#pragma unroll
    for (int fm = 0; fm < 3; ++fm) {
        int rowa = wm * 48 + fm * 16 + (lane & 15);
        int rowb = wn * 48 + fm * 16 + (lane & 15);
#pragma unroll
        for (int kk = 0; kk < 2; ++kk) {
            int slot = kk * 4 + (lane >> 4);
            a_off[fm][kk] = rowa * BK + ((slot ^ (rowa & 7)) << 3);
            b_off[fm][kk] = rowb * BK + ((slot ^ (rowb & 7)) << 3);
        }
    }

    f32x4 acc[3][3];
#pragma unroll
    for (int fm = 0; fm < 3; ++fm)
#pragma unroll
        for (int fn = 0; fn < 3; ++fn) acc[fm][fn] = (f32x4)0.f;

    float sa[6], sb[6];
#pragma unroll
    for (int p = 0; p < 6; ++p) { sa[p] = 0.f; sb[p] = 0.f; }

    float4 va[6], vb[6];
    // ---- prologue: tile 0 -> regs -> buf0; issue tile-1 loads; barrier
#pragma unroll
    for (int p = 0; p < 6; ++p) {
        va[p] = *(const float4*)(pa[p]);
        vb[p] = *(const float4*)(pb[p]);
    }
#pragma unroll
    for (int p = 0; p < 6; ++p) {
        sa[p] += va[p].x * va[p].x + va[p].y * va[p].y
               + va[p].z * va[p].z + va[p].w * va[p].w;
        sb[p] += vb[p].x * vb[p].x + vb[p].y * vb[p].y
               + vb[p].z * vb[p].z + vb[p].w * vb[p].w;
        *(bf16x4*)&As[0][wr_off[p]] = bf16x4{ (bf16)va[p].x, (bf16)va[p].y, (bf16)va[p].z, (bf16)va[p].w };
        *(bf16x4*)&Bs[0][wr_off[p]] = bf16x4{ (bf16)vb[p].x, (bf16)vb[p].y, (bf16)vb[p].z, (bf16)vb[p].w };
    }
#pragma unroll
    for (int p = 0; p < 6; ++p) {
        va[p] = *(const float4*)(pa[p] + BK);
        vb[p] = *(const float4*)(pb[p] + BK);
    }
    BARRIER_FULL();

    // ---- main loop: 8 k-steps; loads for t+2 fly across both barriers
#pragma unroll
    for (int kt = 0; kt < 8; ++kt) {
        int cur = kt & 1;
#pragma unroll
        for (int kk = 0; kk < 2; ++kk) {
            bf16x8 af[3], bfr[3];
#pragma unroll
            for (int fm = 0; fm < 3; ++fm) af[fm]  = *(const bf16x8*)&As[cur][a_off[fm][kk]];
#pragma unroll
            for (int fn = 0; fn < 3; ++fn) bfr[fn] = *(const bf16x8*)&Bs[cur][b_off[fn][kk]];
#pragma unroll
            for (int fm = 0; fm < 3; ++fm)
#pragma unroll
                for (int fn = 0; fn < 3; ++fn)
                    acc[fm][fn] = __builtin_amdgcn_mfma_f32_16x16x32_bf16(
                        af[fm], bfr[fn], acc[fm][fn], 0, 0, 0);
        }
        if (kt < 7) {
            BARRIER_LIGHT();   // all reads of buf[cur^1] (prev iter) long done;
                               // now safe to overwrite buf[cur^1] below
            // cvt + norms for tile kt+1 (compiler auto-waits its loads here)
#pragma unroll
            for (int p = 0; p < 6; ++p) {
                sa[p] += va[p].x * va[p].x + va[p].y * va[p].y
                       + va[p].z * va[p].z + va[p].w * va[p].w;
                sb[p] += vb[p].x * vb[p].x + vb[p].y * vb[p].y
                       + vb[p].z * vb[p].z + vb[p].w * vb[p].w;
                *(bf16x4*)&As[cur ^ 1][wr_off[p]] = bf16x4{ (bf16)va[p].x, (bf16)va[p].y, (bf16)va[p].z, (bf16)va[p].w };
                *(bf16x4*)&Bs[cur ^ 1][wr_off[p]] = bf16x4{ (bf16)vb[p].x, (bf16)vb[p].y, (bf16)vb[p].z, (bf16)vb[p].w };
            }
            if (kt < 6) {
                int knext = (kt + 2) * BK;
#pragma unroll
                for (int p = 0; p < 6; ++p) {
                    va[p] = *(const float4*)(pa[p] + knext);
                    vb[p] = *(const float4*)(pb[p] + knext);
                }
            }
            BARRIER_FULL();    // ds_writes visible before next iter's reads
        }
    }

    // ---- norm reduce across the 16 lanes sharing a staging row -> LDS
#pragma unroll
    for (int p = 0; p < 6; ++p) {
        float v1 = sa[p], v2 = sb[p];
        v1 += __shfl_xor(v1, 1); v1 += __shfl_xor(v1, 2);
        v1 += __shfl_xor(v1, 4); v1 += __shfl_xor(v1, 8);
        v2 += __shfl_xor(v2, 1); v2 += __shfl_xor(v2, 2);
        v2 += __shfl_xor(v2, 4); v2 += __shfl_xor(v2, 8);
        if ((t & 15) == 0) {
            na_s[p * 16 + (t >> 4)] = v1;
            nb_s[p * 16 + (t >> 4)] = v2;
        }
    }
    __syncthreads();

    // ---- epilogue: A_ij = 1/(1+dist), masked; row/col partial sums
    int b_off_w = b * M;
    float na_[3][4], nb_[3];
#pragma unroll
    for (int fm = 0; fm < 3; ++fm)
#pragma unroll
        for (int r = 0; r < 4; ++r)
            na_[fm][r] = na_s[wm * 48 + fm * 16 + (lane >> 4) * 4 + r];
#pragma unroll
    for (int fn = 0; fn < 3; ++fn)
        nb_[fn] = nb_s[wn * 48 + fn * 16 + (lane & 15)];

    float rs[3][4], cs[3];
#pragma unroll
    for (int fm = 0; fm < 3; ++fm)
#pragma unroll
        for (int r = 0; r < 4; ++r) rs[fm][r] = 0.f;
#pragma unroll
    for (int fn = 0; fn < 3; ++fn) cs[fn] = 0.f;

#pragma unroll
    for (int fm = 0; fm < 3; ++fm) {
#pragma unroll
        for (int fn = 0; fn < 3; ++fn) {
#pragma unroll
            for (int r = 0; r < 4; ++r) {
                int i = iw + fm * 16 + (lane >> 4) * 4 + r;
                int j = jw + fn * 16 + (lane & 15);
                float av = 0.f;
                if (i < M && j < M) {
                    float sq   = na_[fm][r] + nb_[fn] - 2.f * acc[fm][fn][r];
                    float dist = sqrtf(fmaxf(sq, 0.f));
                    av = 1.f / (1.f + dist);
                }
                rs[fm][r] += av;
                cs[fn]    += av;
            }
        }
    }

#pragma unroll
    for (int fm = 0; fm < 3; ++fm)
#pragma unroll
        for (int r = 0; r < 4; ++r) {
            float v = rs[fm][r];
            v += __shfl_xor(v, 1); v += __shfl_xor(v, 2);
            v += __shfl_xor(v, 4); v += __shfl_xor(v, 8);
            int i = iw + fm * 16 + (lane >> 4) * 4 + r;
            if ((lane & 15) == 0 && i < M) atomicAdd(&ws[NM + b_off_w + i], v);  // wrow
        }
#pragma unroll
    for (int fn = 0; fn < 3; ++fn) {
        float v = cs[fn];
        v += __shfl_xor(v, 16); v += __shfl_xor(v, 32);
        int j = jw + fn * 16 + (lane & 15);
        if ((lane >> 4) == 0 && j < M) atomicAdd(&ws[b_off_w + j], v);           // wcol
    }
}

// ---------------- Kernel 2: sliding-window weighted sum (float4) -----------
__global__ void k_out(const float* __restrict__ x1, const float* __restrict__ x2,
                      const float* __restrict__ ws, float* __restrict__ out) {
    int bid   = blockIdx.x;
    int which = bid & 1;
    int tc    = (bid >> 1) & 7;
    int b     = bid >> 4;
    int d4    = threadIdx.x << 2;
    const float* src  = which ? x2 : x1;
    const float* wgt  = ws + (which ? NM : 0) + b * M;
    const float* rows = src + (size_t)b * M * D + d4;
    float* o = out + (size_t)which * OUTHALF + ((size_t)b * T + tc * 32) * D + d4;
    int t0 = tc * 32;
    float4 v0 = *(const float4*)(rows + (size_t)(t0 + 0) * D);
    float4 v1 = *(const float4*)(rows + (size_t)(t0 + 1) * D);
    float4 v2 = *(const float4*)(rows + (size_t)(t0 + 2) * D);
    float s0 = wgt[t0 + 0], s1 = wgt[t0 + 1], s2 = wgt[t0 + 2];
#pragma unroll 4
    for (int tt = 0; tt < 32; ++tt) {
        float4 v3 = *(const float4*)(rows + (size_t)(t0 + tt + 3) * D);
        float s3  = wgt[t0 + tt + 3];
        float4 r;
        r.x = s0 * v0.x + s1 * v1.x + s2 * v2.x + s3 * v3.x;
        r.y = s0 * v0.y + s1 * v1.y + s2 * v2.y + s3 * v3.y;
        r.z = s0 * v0.z + s1 * v1.z + s2 * v2.z + s3 * v3.z;
        r.w = s0 * v0.w + s1 * v1.w + s2 * v2.w + s3 * v3.w;
        *(float4*)(o + (size_t)tt * D) = r;
        v0 = v1; v1 = v2; v2 = v3;
        s0 = s1; s1 = s2; s2 = s3;
    }
}

extern "C" void kernel_launch(void* const* d_in, const int* in_sizes, int n_in,
                              void* d_out, int out_size, void* d_ws, size_t ws_size,
                              hipStream_t stream) {
    const float* x1 = (const float*)d_in[0];
    const float* x2 = (const float*)d_in[1];
    float* out = (float*)d_out;
    float* ws  = (float*)d_ws;

    k_zero<<<(2 * NM / 4 + 255) / 256, 256, 0, stream>>>((float4*)ws);   // 65 blocks
    k_pairs<<<BATCH * NTL * NTL, 256, 0, stream>>>(x1, x2, ws);          // 1152 blocks
    k_out<<<BATCH * 16, 128, 0, stream>>>(x1, x2, ws, out);              // 2048 blocks
}

// Round 9
// 119.310 us; speedup vs baseline: 1.3311x; 1.3311x over previous
//
#include <hip/hip_runtime.h>

#define BATCH 128
#define M 259
#define D 512
#define T 256
#define NM (BATCH * M)          // 33152
#define OUTHALF (BATCH * T * D)

typedef __bf16 bf16;
typedef __bf16 bf16x4 __attribute__((ext_vector_type(4)));
typedef __bf16 bf16x8 __attribute__((ext_vector_type(8)));
typedef float f32x4 __attribute__((ext_vector_type(4)));

// ws float layout: na[NM] | nb[NM] | wcol[NM] | wrow[NM]

// ---------------- Kernel 1: norms + zero accumulators (proven, 25 us) ------
__global__ void k_norms(const float* __restrict__ x1, const float* __restrict__ x2,
                        float* __restrict__ ws) {
    int row  = blockIdx.x * 4 + (threadIdx.x >> 6);
    int lane = threadIdx.x & 63;
    if (row >= NM) return;
    const float4* p1 = (const float4*)(x1 + (size_t)row * D);
    const float4* p2 = (const float4*)(x2 + (size_t)row * D);
    float s1 = 0.f, s2 = 0.f;
#pragma unroll
    for (int q = 0; q < 2; ++q) {
        float4 v = p1[lane + q * 64];
        s1 += v.x * v.x + v.y * v.y + v.z * v.z + v.w * v.w;
        float4 u = p2[lane + q * 64];
        s2 += u.x * u.x + u.y * u.y + u.z * u.z + u.w * u.w;
    }
#pragma unroll
    for (int off = 32; off > 0; off >>= 1) {
        s1 += __shfl_xor(s1, off);
        s2 += __shfl_xor(s2, off);
    }
    if (lane == 0) {
        ws[row]          = s1;
        ws[NM + row]     = s2;
        ws[2 * NM + row] = 0.f;  // wcol accumulator
        ws[3 * NM + row] = 0.f;  // wrow accumulator
    }
}

// ---------------- Kernel 2: bf16 MFMA pairwise, 144x144 tiles --------------
// 2x2 tiles/batch -> each panel read 2x (was 3x at 96): traffic 442->295 MB.
// 576 threads = 9 waves of 48x48. Proven r2 loop order; proven r5 geometry
// (r5 passed correctness; its regression was launch_bounds-induced spill).
#define BT 144
#define BK 64

__global__ void k_pairs(const float* __restrict__ x1, const float* __restrict__ x2,
                        float* __restrict__ ws) {
    __shared__ __align__(16) bf16 As[BT * BK];   // 18 KB
    __shared__ __align__(16) bf16 Bs[BT * BK];   // 18 KB

    int s   = blockIdx.x;                 // 512 = 8 * 64, bijective XCD swizzle
    int bid = (s & 7) * 64 + (s >> 3);
    int b   = bid >> 2;
    int ti  = (bid >> 1) & 1;
    int tj  = bid & 1;
    int i0  = ti * BT, j0 = tj * BT;

    int t    = threadIdx.x;
    int lane = t & 63;
    int w    = t / 64;                    // 0..8
    int wm   = w / 3, wn = w % 3;         // 3x3 wave grid, 48x48 per wave
    int iw   = i0 + wm * 48;
    int jw   = j0 + wn * 48;

    const float* Ab = x1 + (size_t)b * M * D;
    const float* Bb = x2 + (size_t)b * M * D;

    // staging: 4 passes of 36 rows x 64 cols per matrix, 1 float4/thread/pass
    const float* pa[4];
    const float* pb[4];
    int c4 = (t & 15) * 4;
#pragma unroll
    for (int p = 0; p < 4; ++p) {
        int row = p * 36 + (t >> 4);      // [0,144)
        int ra = min(i0 + row, M - 1);
        int rb = min(j0 + row, M - 1);
        pa[p] = Ab + (size_t)ra * D + c4;
        pb[p] = Bb + (size_t)rb * D + c4;
    }
    int wslot   = (t & 15) >> 1;
    int wwithin = (t & 1) * 4;
    int wr_off[4];
#pragma unroll
    for (int p = 0; p < 4; ++p) {
        int row = p * 36 + (t >> 4);
        wr_off[p] = row * BK + ((wslot ^ (row & 7)) << 3) + wwithin;
    }

    // fragment read offsets (element units), swizzle-matched (proven formula)
    int a_off[3][2], b_off[3][2];
#pragma unroll
    for (int fm = 0; fm < 3; ++fm) {
        int rowa = wm * 48 + fm * 16 + (lane & 15);
        int rowb = wn * 48 + fm * 16 + (lane & 15);
#pragma unroll
        for (int kk = 0; kk < 2; ++kk) {
            int slot = kk * 4 + (lane >> 4);
            a_off[fm][kk] = rowa * BK + ((slot ^ (rowa & 7)) << 3);
            b_off[fm][kk] = rowb * BK + ((slot ^ (rowb & 7)) << 3);
        }
    }

    f32x4 acc[3][3];
#pragma unroll
    for (int fm = 0; fm < 3; ++fm)
#pragma unroll
        for (int fn = 0; fn < 3; ++fn) acc[fm][fn] = (f32x4)0.f;

    for (int k0 = 0; k0 < D; k0 += BK) {
        float4 va[4], vb[4];
#pragma unroll
        for (int p = 0; p < 4; ++p) {
            va[p] = *(const float4*)(pa[p] + k0);
            vb[p] = *(const float4*)(pb[p] + k0);
        }
        __syncthreads();
#pragma unroll
        for (int p = 0; p < 4; ++p) {
            *(bf16x4*)&As[wr_off[p]] = bf16x4{ (bf16)va[p].x, (bf16)va[p].y, (bf16)va[p].z, (bf16)va[p].w };
            *(bf16x4*)&Bs[wr_off[p]] = bf16x4{ (bf16)vb[p].x, (bf16)vb[p].y, (bf16)vb[p].z, (bf16)vb[p].w };
        }
        __syncthreads();
#pragma unroll
        for (int kk = 0; kk < 2; ++kk) {
            bf16x8 af[3], bfr[3];
#pragma unroll
            for (int fm = 0; fm < 3; ++fm) af[fm]  = *(const bf16x8*)&As[a_off[fm][kk]];
#pragma unroll
            for (int fn = 0; fn < 3; ++fn) bfr[fn] = *(const bf16x8*)&Bs[b_off[fn][kk]];
#pragma unroll
            for (int fm = 0; fm < 3; ++fm)
#pragma unroll
                for (int fn = 0; fn < 3; ++fn)
                    acc[fm][fn] = __builtin_amdgcn_mfma_f32_16x16x32_bf16(
                        af[fm], bfr[fn], acc[fm][fn], 0, 0, 0);
        }
    }

    // epilogue: A_ij = 1/(1+dist), masked; row/col partial sums (proven)
    int b_off_w = b * M;
    float na_[3][4], nb_[3];
#pragma unroll
    for (int fm = 0; fm < 3; ++fm)
#pragma unroll
        for (int r = 0; r < 4; ++r) {
            int i = iw + fm * 16 + (lane >> 4) * 4 + r;
            na_[fm][r] = (i < M) ? ws[b_off_w + i] : 0.f;
        }
#pragma unroll
    for (int fn = 0; fn < 3; ++fn) {
        int j = jw + fn * 16 + (lane & 15);
        nb_[fn] = (j < M) ? ws[NM + b_off_w + j] : 0.f;
    }

    float rs[3][4], cs[3];
#pragma unroll
    for (int fm = 0; fm < 3; ++fm)
#pragma unroll
        for (int r = 0; r < 4; ++r) rs[fm][r] = 0.f;
#pragma unroll
    for (int fn = 0; fn < 3; ++fn) cs[fn] = 0.f;

#pragma unroll
    for (int fm = 0; fm < 3; ++fm) {
#pragma unroll
        for (int fn = 0; fn < 3; ++fn) {
#pragma unroll
            for (int r = 0; r < 4; ++r) {
                int i = iw + fm * 16 + (lane >> 4) * 4 + r;
                int j = jw + fn * 16 + (lane & 15);
                float av = 0.f;
                if (i < M && j < M) {
                    float sq   = na_[fm][r] + nb_[fn] - 2.f * acc[fm][fn][r];
                    float dist = sqrtf(fmaxf(sq, 0.f));
                    av = 1.f / (1.f + dist);
                }
                rs[fm][r] += av;
                cs[fn]    += av;
            }
        }
    }

#pragma unroll
    for (int fm = 0; fm < 3; ++fm)
#pragma unroll
        for (int r = 0; r < 4; ++r) {
            float v = rs[fm][r];
            v += __shfl_xor(v, 1); v += __shfl_xor(v, 2);
            v += __shfl_xor(v, 4); v += __shfl_xor(v, 8);
            int i = iw + fm * 16 + (lane >> 4) * 4 + r;
            if ((lane & 15) == 0 && i < M) atomicAdd(&ws[3 * NM + b_off_w + i], v);  // wrow
        }
#pragma unroll
    for (int fn = 0; fn < 3; ++fn) {
        float v = cs[fn];
        v += __shfl_xor(v, 16); v += __shfl_xor(v, 32);
        int j = jw + fn * 16 + (lane & 15);
        if ((lane >> 4) == 0 && j < M) atomicAdd(&ws[2 * NM + b_off_w + j], v);      // wcol
    }
}

// ---------------- Kernel 3: sliding-window weighted sum (float4, 13 us) ----
__global__ void k_out(const float* __restrict__ x1, const float* __restrict__ x2,
                      const float* __restrict__ ws, float* __restrict__ out) {
    int bid   = blockIdx.x;
    int which = bid & 1;
    int tc    = (bid >> 1) & 7;
    int b     = bid >> 4;
    int d4    = threadIdx.x << 2;
    const float* src  = which ? x2 : x1;
    const float* wgt  = ws + (which ? 3 * NM : 2 * NM) + b * M;
    const float* rows = src + (size_t)b * M * D + d4;
    float* o = out + (size_t)which * OUTHALF + ((size_t)b * T + tc * 32) * D + d4;
    int t0 = tc * 32;
    float4 v0 = *(const float4*)(rows + (size_t)(t0 + 0) * D);
    float4 v1 = *(const float4*)(rows + (size_t)(t0 + 1) * D);
    float4 v2 = *(const float4*)(rows + (size_t)(t0 + 2) * D);
    float s0 = wgt[t0 + 0], s1 = wgt[t0 + 1], s2 = wgt[t0 + 2];
#pragma unroll 4
    for (int tt = 0; tt < 32; ++tt) {
        float4 v3 = *(const float4*)(rows + (size_t)(t0 + tt + 3) * D);
        float s3  = wgt[t0 + tt + 3];
        float4 r;
        r.x = s0 * v0.x + s1 * v1.x + s2 * v2.x + s3 * v3.x;
        r.y = s0 * v0.y + s1 * v1.y + s2 * v2.y + s3 * v3.y;
        r.z = s0 * v0.z + s1 * v1.z + s2 * v2.z + s3 * v3.z;
        r.w = s0 * v0.w + s1 * v1.w + s2 * v2.w + s3 * v3.w;
        *(float4*)(o + (size_t)tt * D) = r;
        v0 = v1; v1 = v2; v2 = v3;
        s0 = s1; s1 = s2; s2 = s3;
    }
}

extern "C" void kernel_launch(void* const* d_in, const int* in_sizes, int n_in,
                              void* d_out, int out_size, void* d_ws, size_t ws_size,
                              hipStream_t stream) {
    const float* x1 = (const float*)d_in[0];
    const float* x2 = (const float*)d_in[1];
    float* out = (float*)d_out;
    float* ws  = (float*)d_ws;

    k_norms<<<NM / 4, 256, 0, stream>>>(x1, x2, ws);      // 8288 blocks
    k_pairs<<<512, 576, 0, stream>>>(x1, x2, ws);         // 512 blocks, 2/CU
    k_out<<<BATCH * 16, 128, 0, stream>>>(x1, x2, ws, out); // 2048 blocks
}

// Round 10
// 103.663 us; speedup vs baseline: 1.5320x; 1.1509x over previous
//
#include <hip/hip_runtime.h>

#define BATCH 128
#define M 259
#define D 512
#define T 256
#define NM (BATCH * M)          // 33152
#define OUTHALF (BATCH * T * D)
#define MP 320                  // padded A rows (i)
#define HJ 160                  // padded B rows per j-half
#define PROWS 480               // MP + HJ LDS panel rows
#define BK 64

typedef __bf16 bf16;
typedef __bf16 bf16x4 __attribute__((ext_vector_type(4)));
typedef __bf16 bf16x8 __attribute__((ext_vector_type(8)));
typedef float f32x4 __attribute__((ext_vector_type(4)));

// ws float layout: wcol[NM] | wrow[NM]

// ---------------- Kernel 0: zero wrow accumulators only --------------------
__global__ void k_zero(float* __restrict__ ws) {
    int i = blockIdx.x * 256 + threadIdx.x;
    if (i < NM) ws[NM + i] = 0.f;
}

// ---------------- Kernel 1: batch-panel MFMA + fused norms + sums ----------
// One WG per (batch, j-half). Stages full A panel (320 pad rows) + B half
// (160 pad rows) per K-slice -> every input byte read once per WG.
__launch_bounds__(512)
__global__ void k_pairs(const float* __restrict__ x1, const float* __restrict__ x2,
                        float* __restrict__ ws) {
    __shared__ __align__(16) bf16 P[PROWS * BK];   // 60 KB
    __shared__ float nrm[PROWS];
    __shared__ float wcol_s[HJ];

    int sblk = blockIdx.x;                 // 256 = 8 * 32, bijective XCD swizzle
    int bid  = (sblk & 7) * 32 + (sblk >> 3);
    int b  = bid >> 1;
    int jh = bid & 1;
    int j0 = jh * 130;

    int t    = threadIdx.x;                // 512 threads = 8 waves
    int lane = t & 63;
    int w    = t >> 6;
    int wm   = w >> 1;                     // 4 i-strips of 80
    int wn   = w & 1;                      // 2 j-strips of 80

    const float* Ab = x1 + (size_t)b * M * D;
    const float* Bb = x2 + (size_t)b * M * D;

    if (t < HJ) wcol_s[t] = 0.f;

    // staging map: 480 rows x 16 float4-cols; thread t covers rows q+32p,
    // f4-col c4f, p=0..14 (p<10 = A panel, p>=10 = B half panel).
    int q = t >> 4, c4f = t & 15;
    int off[15], wro[15];
#pragma unroll
    for (int p = 0; p < 15; ++p) {
        int row  = q + 32 * p;             // LDS panel row
        int grow = (p < 10) ? min(row, M - 1) : min(j0 + (row - MP), M - 1);
        off[p] = grow * D + c4f * 4;       // float index into source matrix
        wro[p] = row * BK + (((c4f >> 1) ^ (row & 7)) << 3) + (t & 1) * 4;
    }

    // fragment read offsets (proven swizzle-matched formula)
    int a_off[5][2], b_off[5][2];
#pragma unroll
    for (int f = 0; f < 5; ++f) {
        int rowa = wm * 80 + f * 16 + (lane & 15);
        int rowb = MP + wn * 80 + f * 16 + (lane & 15);
#pragma unroll
        for (int kk = 0; kk < 2; ++kk) {
            int slot = kk * 4 + (lane >> 4);
            a_off[f][kk] = rowa * BK + ((slot ^ (rowa & 7)) << 3);
            b_off[f][kk] = rowb * BK + ((slot ^ (rowb & 7)) << 3);
        }
    }

    f32x4 acc[5][5];
#pragma unroll
    for (int fi = 0; fi < 5; ++fi)
#pragma unroll
        for (int fj = 0; fj < 5; ++fj) acc[fi][fj] = (f32x4)0.f;

    float sa[15];
#pragma unroll
    for (int p = 0; p < 15; ++p) sa[p] = 0.f;

#define STAGE5(P0, BASE) do {                                                   \
        float4 v_[5];                                                           \
        _Pragma("unroll")                                                       \
        for (int i_ = 0; i_ < 5; ++i_)                                          \
            v_[i_] = *(const float4*)((BASE) + off[(P0) + i_] + k0);            \
        _Pragma("unroll")                                                       \
        for (int i_ = 0; i_ < 5; ++i_) {                                        \
            sa[(P0) + i_] += v_[i_].x * v_[i_].x + v_[i_].y * v_[i_].y          \
                           + v_[i_].z * v_[i_].z + v_[i_].w * v_[i_].w;         \
            *(bf16x4*)&P[wro[(P0) + i_]] = bf16x4{ (bf16)v_[i_].x,              \
                (bf16)v_[i_].y, (bf16)v_[i_].z, (bf16)v_[i_].w };               \
        } } while (0)

    for (int k0 = 0; k0 < D; k0 += BK) {
        __syncthreads();            // prev slice's LDS reads complete
        STAGE5(0, Ab);              // A rows 0..159
        STAGE5(5, Ab);              // A rows 160..319
        STAGE5(10, Bb);             // B half rows
        __syncthreads();            // panel visible
#pragma unroll
        for (int kk = 0; kk < 2; ++kk) {
            bf16x8 af[5], bfr[5];
#pragma unroll
            for (int f = 0; f < 5; ++f) af[f]  = *(const bf16x8*)&P[a_off[f][kk]];
#pragma unroll
            for (int f = 0; f < 5; ++f) bfr[f] = *(const bf16x8*)&P[b_off[f][kk]];
#pragma unroll
            for (int fi = 0; fi < 5; ++fi)
#pragma unroll
                for (int fj = 0; fj < 5; ++fj)
                    acc[fi][fj] = __builtin_amdgcn_mfma_f32_16x16x32_bf16(
                        af[fi], bfr[fj], acc[fi][fj], 0, 0, 0);
        }
    }
#undef STAGE5

    // norms: reduce each staged row over its 16 covering lanes -> nrm[]
#pragma unroll
    for (int p = 0; p < 15; ++p) {
        float v = sa[p];
        v += __shfl_xor(v, 1); v += __shfl_xor(v, 2);
        v += __shfl_xor(v, 4); v += __shfl_xor(v, 8);
        if ((t & 15) == 0) nrm[q + 32 * p] = v;
    }
    __syncthreads();

    // epilogue: A_ij = 1/(1+dist), masked; wave-local row/col sums
    float na_[5][4], nb_[5];
#pragma unroll
    for (int f = 0; f < 5; ++f) {
#pragma unroll
        for (int r = 0; r < 4; ++r)
            na_[f][r] = nrm[wm * 80 + f * 16 + (lane >> 4) * 4 + r];
        nb_[f] = nrm[MP + wn * 80 + f * 16 + (lane & 15)];
    }

    float rs[5][4], cs[5];
#pragma unroll
    for (int f = 0; f < 5; ++f) {
#pragma unroll
        for (int r = 0; r < 4; ++r) rs[f][r] = 0.f;
        cs[f] = 0.f;
    }

#pragma unroll
    for (int fi = 0; fi < 5; ++fi) {
#pragma unroll
        for (int fj = 0; fj < 5; ++fj) {
#pragma unroll
            for (int r = 0; r < 4; ++r) {
                int i  = wm * 80 + fi * 16 + (lane >> 4) * 4 + r;
                int lj = wn * 80 + fj * 16 + (lane & 15);
                int jg = j0 + lj;
                float av = 0.f;
                if (i < M && lj < 130 && jg < M) {
                    float sq   = na_[fi][r] + nb_[fj] - 2.f * acc[fi][fj][r];
                    float dist = sqrtf(fmaxf(sq, 0.f));
                    av = 1.f / (1.f + dist);
                }
                rs[fi][r] += av;
                cs[fj]    += av;
            }
        }
    }

    int b_off_w = b * M;
    // wrow (sum over j, partial per j-half): reduce over lane&15, global atomic
#pragma unroll
    for (int f = 0; f < 5; ++f)
#pragma unroll
        for (int r = 0; r < 4; ++r) {
            float v = rs[f][r];
            v += __shfl_xor(v, 1); v += __shfl_xor(v, 2);
            v += __shfl_xor(v, 4); v += __shfl_xor(v, 8);
            int i = wm * 80 + f * 16 + (lane >> 4) * 4 + r;
            if ((lane & 15) == 0 && i < M) atomicAdd(&ws[NM + b_off_w + i], v);
        }
    // wcol (sum over i): reduce over lane>>4, accumulate across wm via LDS
#pragma unroll
    for (int f = 0; f < 5; ++f) {
        float v = cs[f];
        v += __shfl_xor(v, 16); v += __shfl_xor(v, 32);
        if ((lane >> 4) == 0)
            atomicAdd(&wcol_s[wn * 80 + f * 16 + (lane & 15)], v);
    }
    __syncthreads();
    if (t < HJ && t < 130 && j0 + t < M) ws[b_off_w + j0 + t] = wcol_s[t];
}

// ---------------- Kernel 2: sliding-window weighted sum (float4, proven) ---
__global__ void k_out(const float* __restrict__ x1, const float* __restrict__ x2,
                      const float* __restrict__ ws, float* __restrict__ out) {
    int bid   = blockIdx.x;
    int which = bid & 1;
    int tc    = (bid >> 1) & 7;
    int b     = bid >> 4;
    int d4    = threadIdx.x << 2;
    const float* src  = which ? x2 : x1;
    const float* wgt  = ws + (which ? NM : 0) + b * M;
    const float* rows = src + (size_t)b * M * D + d4;
    float* o = out + (size_t)which * OUTHALF + ((size_t)b * T + tc * 32) * D + d4;
    int t0 = tc * 32;
    float4 v0 = *(const float4*)(rows + (size_t)(t0 + 0) * D);
    float4 v1 = *(const float4*)(rows + (size_t)(t0 + 1) * D);
    float4 v2 = *(const float4*)(rows + (size_t)(t0 + 2) * D);
    float s0 = wgt[t0 + 0], s1 = wgt[t0 + 1], s2 = wgt[t0 + 2];
#pragma unroll 4
    for (int tt = 0; tt < 32; ++tt) {
        float4 v3 = *(const float4*)(rows + (size_t)(t0 + tt + 3) * D);
        float s3  = wgt[t0 + tt + 3];
        float4 r;
        r.x = s0 * v0.x + s1 * v1.x + s2 * v2.x + s3 * v3.x;
        r.y = s0 * v0.y + s1 * v1.y + s2 * v2.y + s3 * v3.y;
        r.z = s0 * v0.z + s1 * v1.z + s2 * v2.z + s3 * v3.z;
        r.w = s0 * v0.w + s1 * v1.w + s2 * v2.w + s3 * v3.w;
        *(float4*)(o + (size_t)tt * D) = r;
        v0 = v1; v1 = v2; v2 = v3;
        s0 = s1; s1 = s2; s2 = s3;
    }
}

extern "C" void kernel_launch(void* const* d_in, const int* in_sizes, int n_in,
                              void* d_out, int out_size, void* d_ws, size_t ws_size,
                              hipStream_t stream) {
    const float* x1 = (const float*)d_in[0];
    const float* x2 = (const float*)d_in[1];
    float* out = (float*)d_out;
    float* ws  = (float*)d_ws;

    k_zero<<<(NM + 255) / 256, 256, 0, stream>>>(ws);        // 130 blocks
    k_pairs<<<256, 512, 0, stream>>>(x1, x2, ws);            // 1 WG/CU
    k_out<<<BATCH * 16, 128, 0, stream>>>(x1, x2, ws, out);  // 2048 blocks
}